// Round 3
// baseline (564.969 us; speedup 1.0000x reference)
//
#include <hip/hip_runtime.h>
#include <hip/hip_fp16.h>
#include <stdint.h>
#include <stddef.h>

// Mamba block, B=4 L=2048 D=DI=1024 N=8 K=4 R=64. ALL I/O fp32.
// GEMMs: bf16x3 split-precision MFMA (AhiBhi + AhiBlo + AloBhi), fp32 elsewhere,
// dt stored fp16. ws layout (MiB):
//   [0,32)   xn f32 (rmsnorm out) -> reused as y f32 (scan2 out)
//   [32,64)  x f32 (in_proj half 0) -> after conv: dt fp16 at [32,48)
//   [64,96)  z f32 (in_proj half 1)
//   [96,128) xc f32 (conv+silu out)
//   [128,131) dbl f32 [8192,80]
//   [131,133) hF  [133,135) Pb  [135,137) h0
// WS_NEED = 137 MiB.

typedef unsigned short u16;
typedef unsigned int u32;
typedef __attribute__((ext_vector_type(8))) short short8;
typedef __attribute__((ext_vector_type(4))) float f32x4;

#define LSEQ 2048
#define DMODEL 1024
#define NSTATE 8
#define NCHUNK 16
#define CHUNKL 128
#define NROWS 8192
#define WS_NEED (137ull << 20)

__device__ __forceinline__ float bf2f(u16 u) {
    union { u32 i; float f; } v; v.i = ((u32)u) << 16; return v.f;
}
__device__ __forceinline__ u16 f2bf(float f) {
    union { u32 i; float f; } v; v.f = f;
    u32 r = v.i + 0x7FFFu + ((v.i >> 16) & 1u);
    return (u16)(r >> 16);
}

// diagnostic: ws too small -> unmistakable finite absmax (~999)
__global__ __launch_bounds__(256) void sentinel_kernel(float* __restrict__ out, int n) {
    int i = blockIdx.x * 256 + threadIdx.x;
    if (i < n) out[i] = 999.0f;
}

// ---------------- RMSNorm fp32: hidden[8192,1024] -> xn ----------------
__global__ __launch_bounds__(256) void rmsnorm_kernel(const float* __restrict__ X,
                                                      const float* __restrict__ W,
                                                      float* __restrict__ O) {
    const int row = blockIdx.x;
    const int tid = threadIdx.x;
    f32x4 u = *(const f32x4*)(X + (size_t)row * DMODEL + tid * 4);
    float ss = u[0]*u[0] + u[1]*u[1] + u[2]*u[2] + u[3]*u[3];
    for (int off = 32; off; off >>= 1) ss += __shfl_down(ss, off, 64);
    __shared__ float red[4];
    if ((tid & 63) == 0) red[tid >> 6] = ss;
    __syncthreads();
    float tot = red[0] + red[1] + red[2] + red[3];
    float scale = rsqrtf(tot * (1.0f / DMODEL) + 1e-5f);
    f32x4 w = *(const f32x4*)(W + tid * 4);
    f32x4 o;
    o[0] = u[0] * scale * w[0]; o[1] = u[1] * scale * w[1];
    o[2] = u[2] * scale * w[2]; o[3] = u[3] * scale * w[3];
    *(f32x4*)(O + (size_t)row * DMODEL + tid * 4) = o;
}

// ---------- bf16x3 GEMM (B^T form): C[m,n] = sum_k A[m,k]*Bm[n,k], fp32 in --
// tile 128x128, BK=32, 256 threads (4 waves 2x2 of 64x64), mfma 16x16x32 bf16,
// three passes: AhiBhi + AhiBlo + AloBhi. EPI 0: fp32 store. EPI 1: fp16
// softplus(acc+bias).
template <int EPI>
__global__ __launch_bounds__(256) void gemm_x3(const float* __restrict__ A, int lda,
                                               const float* __restrict__ Bm, int ldb,
                                               void* __restrict__ Cp, int ldc,
                                               int N, int K,
                                               const float* __restrict__ bias) {
    __shared__ alignas(16) u16 sAh[128 * 32];
    __shared__ alignas(16) u16 sAl[128 * 32];
    __shared__ alignas(16) u16 sBh[128 * 32];
    __shared__ alignas(16) u16 sBl[128 * 32];
    const int tid = threadIdx.x;
    const int wave = tid >> 6, lane = tid & 63;
    const int wm = (wave >> 1) * 64, wn = (wave & 1) * 64;
    const int tm = blockIdx.x, tn = blockIdx.y;
    const int q = lane >> 4, cl = lane & 15;

    f32x4 acc[4][4];
    const f32x4 zero4 = {0.f, 0.f, 0.f, 0.f};
#pragma unroll
    for (int t = 0; t < 4; t++)
#pragma unroll
        for (int u = 0; u < 4; u++) acc[t][u] = zero4;

    // staging: 8-element chunks. 128 rows x 4 chunks = 512 chunks, 2/thread.
    int rowS[2], slotS[2], gkS[2];
#pragma unroll
    for (int i = 0; i < 2; i++) {
        int c = i * 256 + tid;
        rowS[i] = c >> 2;
        slotS[i] = c & 3;
        gkS[i] = slotS[i] ^ (rowS[i] & 3);   // global k-chunk stored in this slot
    }

    for (int k0 = 0; k0 < K; k0 += 32) {
        f32x4 a0[2], a1[2], b0[2], b1[2];
#pragma unroll
        for (int i = 0; i < 2; i++) {
            int grA = tm * 128 + rowS[i];
            const float* pa = A + (size_t)grA * lda + k0 + gkS[i] * 8;
            a0[i] = *(const f32x4*)pa; a1[i] = *(const f32x4*)(pa + 4);
            int grB = tn * 128 + rowS[i];
            if (grB >= N) grB = N - 1;       // clamp (garbage cols never stored)
            const float* pb = Bm + (size_t)grB * ldb + k0 + gkS[i] * 8;
            b0[i] = *(const f32x4*)pb; b1[i] = *(const f32x4*)(pb + 4);
        }
        __syncthreads();   // previous iter's fragment reads complete
#pragma unroll
        for (int i = 0; i < 2; i++) {
            short8 ah, al, bh, bl;
#pragma unroll
            for (int j = 0; j < 8; j++) {
                float va = (j < 4) ? a0[i][j] : a1[i][j - 4];
                u16 h = f2bf(va); ah[j] = (short)h; al[j] = (short)f2bf(va - bf2f(h));
                float vb = (j < 4) ? b0[i][j] : b1[i][j - 4];
                u16 g = f2bf(vb); bh[j] = (short)g; bl[j] = (short)f2bf(vb - bf2f(g));
            }
            int off = rowS[i] * 32 + slotS[i] * 8;
            *(short8*)(sAh + off) = ah; *(short8*)(sAl + off) = al;
            *(short8*)(sBh + off) = bh; *(short8*)(sBl + off) = bl;
        }
        __syncthreads();

        short8 fah[4], fal[4], fbh[4], fbl[4];
#pragma unroll
        for (int t = 0; t < 4; t++) {
            int m = wm + t * 16 + cl;
            int so = m * 32 + ((q ^ (m & 3)) << 3);
            fah[t] = *(const short8*)(sAh + so);
            fal[t] = *(const short8*)(sAl + so);
            int n = wn + t * 16 + cl;
            int sn = n * 32 + ((q ^ (n & 3)) << 3);
            fbh[t] = *(const short8*)(sBh + sn);
            fbl[t] = *(const short8*)(sBl + sn);
        }
#pragma unroll
        for (int t = 0; t < 4; t++)
#pragma unroll
            for (int u = 0; u < 4; u++) {
                acc[t][u] = __builtin_amdgcn_mfma_f32_16x16x32_bf16(fah[t], fbh[u], acc[t][u], 0, 0, 0);
                acc[t][u] = __builtin_amdgcn_mfma_f32_16x16x32_bf16(fah[t], fbl[u], acc[t][u], 0, 0, 0);
                acc[t][u] = __builtin_amdgcn_mfma_f32_16x16x32_bf16(fal[t], fbh[u], acc[t][u], 0, 0, 0);
            }
    }

    const int rowbase = tm * 128 + wm + q * 4;
    const int colbase = tn * 128 + wn + cl;
    if (EPI == 0) {
        float* Co = (float*)Cp;
#pragma unroll
        for (int t = 0; t < 4; t++)
#pragma unroll
            for (int r = 0; r < 4; r++) {
                size_t rb_ = (size_t)(rowbase + t * 16 + r) * ldc;
#pragma unroll
                for (int u = 0; u < 4; u++) {
                    int gcol = colbase + u * 16;
                    if (gcol < N) Co[rb_ + gcol] = acc[t][u][r];
                }
            }
    } else {
        __half* Co = (__half*)Cp;
#pragma unroll
        for (int t = 0; t < 4; t++)
#pragma unroll
            for (int r = 0; r < 4; r++) {
                size_t rb_ = (size_t)(rowbase + t * 16 + r) * ldc;
#pragma unroll
                for (int u = 0; u < 4; u++) {
                    int gcol = colbase + u * 16;
                    if (gcol < N) {
                        float v = acc[t][u][r] + bias[gcol];
                        v = (v > 15.f) ? v : log1pf(__expf(v));
                        Co[rb_ + gcol] = __float2half(v);
                    }
                }
            }
    }
}

// ------------- causal depthwise conv (K=4) + bias + silu, fp32 --------------
__global__ __launch_bounds__(256) void conv_silu_kernel(const float* __restrict__ x,
                                                        const float* __restrict__ cw,
                                                        const float* __restrict__ cb,
                                                        float* __restrict__ xc) {
    const int row = blockIdx.x;                 // b*2048 + l
    const int d = blockIdx.y * 256 + threadIdx.x;
    const int l = row & (LSEQ - 1);
    float acc = cb[d];
#pragma unroll
    for (int j = 0; j < 4; j++) {
        int ll = l - 3 + j;
        if (ll >= 0)
            acc += cw[d * 4 + j] * x[(size_t)(row - 3 + j) * 1024 + d];
    }
    xc[(size_t)row * 1024 + d] = acc / (1.f + __expf(-acc));
}

// ---------------- selective scan, chunked (fp32 state) ----------------------
__global__ __launch_bounds__(256) void scan1_kernel(const __half* __restrict__ dt,
                                                    const float* __restrict__ xc,
                                                    const float* __restrict__ dbl,
                                                    const float* __restrict__ A_log,
                                                    float* __restrict__ hF,
                                                    float* __restrict__ Pb) {
    const int d = blockIdx.x * 256 + threadIdx.x;
    const int c = blockIdx.y;
    const int b = blockIdx.z;
    float Aa[NSTATE];
#pragma unroll
    for (int n = 0; n < NSTATE; n++) Aa[n] = -__expf(A_log[d * NSTATE + n]);
    float h[NSTATE], P[NSTATE];
#pragma unroll
    for (int n = 0; n < NSTATE; n++) { h[n] = 0.f; P[n] = 1.f; }
    const int l0 = c * CHUNKL;
    for (int l = l0; l < l0 + CHUNKL; l++) {
        int rowb = b * LSEQ + l;
        float dtv = __half2float(dt[(size_t)rowb * 1024 + d]);
        float xv = xc[(size_t)rowb * 1024 + d];
        const f32x4* qp = (const f32x4*)(dbl + (size_t)rowb * 80 + 64);
        f32x4 B0 = qp[0], B1 = qp[1];
        float dtx = dtv * xv;
#pragma unroll
        for (int n = 0; n < NSTATE; n++) {
            float Bn = (n < 4) ? B0[n] : B1[n - 4];
            float e = __expf(Aa[n] * dtv);
            h[n] = e * h[n] + dtx * Bn;
            P[n] *= e;
        }
    }
    size_t base = ((size_t)(b * 1024 + d) * NCHUNK + c) * NSTATE;
#pragma unroll
    for (int n = 0; n < NSTATE; n++) { hF[base + n] = h[n]; Pb[base + n] = P[n]; }
}

__global__ __launch_bounds__(256) void scan_combine_kernel(const float* __restrict__ hF,
                                                           const float* __restrict__ Pb,
                                                           float* __restrict__ h0) {
    const int idx = blockIdx.x * 256 + threadIdx.x;   // b*1024+d
    float carry[NSTATE];
#pragma unroll
    for (int n = 0; n < NSTATE; n++) carry[n] = 0.f;
    for (int c = 0; c < NCHUNK; c++) {
        size_t base = ((size_t)idx * NCHUNK + c) * NSTATE;
#pragma unroll
        for (int n = 0; n < NSTATE; n++) {
            h0[base + n] = carry[n];
            carry[n] = Pb[base + n] * carry[n] + hF[base + n];
        }
    }
}

__global__ __launch_bounds__(256) void scan2_kernel(const __half* __restrict__ dt,
                                                    const float* __restrict__ xc,
                                                    const float* __restrict__ dbl,
                                                    const float* __restrict__ A_log,
                                                    const float* __restrict__ h0,
                                                    const float* __restrict__ z,
                                                    const float* __restrict__ Dsk,
                                                    float* __restrict__ yout) {
    const int d = blockIdx.x * 256 + threadIdx.x;
    const int c = blockIdx.y;
    const int b = blockIdx.z;
    float Aa[NSTATE];
#pragma unroll
    for (int n = 0; n < NSTATE; n++) Aa[n] = -__expf(A_log[d * NSTATE + n]);
    float h[NSTATE];
    {
        size_t base = ((size_t)(b * 1024 + d) * NCHUNK + c) * NSTATE;
#pragma unroll
        for (int n = 0; n < NSTATE; n++) h[n] = h0[base + n];
    }
    const float dval = Dsk[d];
    const int l0 = c * CHUNKL;
    for (int l = l0; l < l0 + CHUNKL; l++) {
        int rowb = b * LSEQ + l;
        float dtv = __half2float(dt[(size_t)rowb * 1024 + d]);
        float xv = xc[(size_t)rowb * 1024 + d];
        const f32x4* qp = (const f32x4*)(dbl + (size_t)rowb * 80 + 64);
        f32x4 B0 = qp[0], B1 = qp[1], C0 = qp[2], C1 = qp[3];
        float dtx = dtv * xv;
        float y = 0.f;
#pragma unroll
        for (int n = 0; n < NSTATE; n++) {
            float Bn = (n < 4) ? B0[n] : B1[n - 4];
            float Cn = (n < 4) ? C0[n] : C1[n - 4];
            float e = __expf(Aa[n] * dtv);
            h[n] = e * h[n] + dtx * Bn;
            y += h[n] * Cn;
        }
        y += dval * xv;
        float zv = z[(size_t)rowb * 1024 + d];
        y *= zv / (1.f + __expf(-zv));
        yout[(size_t)rowb * 1024 + d] = y;
    }
}

extern "C" void kernel_launch(void* const* d_in, const int* in_sizes, int n_in,
                              void* d_out, int out_size, void* d_ws, size_t ws_size,
                              hipStream_t stream) {
    (void)in_sizes; (void)n_in;
    const float* hidden    = (const float*)d_in[0];
    const float* norm_w    = (const float*)d_in[1];
    const float* in_proj_w = (const float*)d_in[2];
    const float* conv_w    = (const float*)d_in[3];
    const float* conv_b    = (const float*)d_in[4];
    const float* x_proj_w  = (const float*)d_in[5];
    const float* dt_proj_w = (const float*)d_in[6];
    const float* dt_proj_b = (const float*)d_in[7];
    const float* A_log     = (const float*)d_in[8];
    const float* D_skip    = (const float*)d_in[9];
    const float* out_proj_w= (const float*)d_in[10];
    float* out = (float*)d_out;

    if (ws_size < WS_NEED) {
        sentinel_kernel<<<dim3((out_size + 255) / 256), 256, 0, stream>>>(out, out_size);
        return;
    }

    char* ws = (char*)d_ws;
    float*  xn   = (float*)(ws);                    // [0,32)  -> y later
    float*  xbuf = (float*)(ws + (32ull << 20));    // [32,64) -> dt fp16 later
    float*  zbuf = (float*)(ws + (64ull << 20));    // [64,96)
    float*  xc   = (float*)(ws + (96ull << 20));    // [96,128)
    float*  dbl  = (float*)(ws + (128ull << 20));   // [128,131)
    float*  hF   = (float*)(ws + (131ull << 20));   // [131,133)
    float*  Pb   = (float*)(ws + (133ull << 20));   // [133,135)
    float*  h0   = (float*)(ws + (135ull << 20));   // [135,137)
    __half* dth  = (__half*)xbuf;                   // reuse after conv
    float*  yb   = xn;                              // reuse after in_proj

    rmsnorm_kernel<<<dim3(NROWS), 256, 0, stream>>>(hidden, norm_w, xn);
    gemm_x3<0><<<dim3(64, 8), 256, 0, stream>>>(xn, 1024, in_proj_w, 1024,
                                                xbuf, 1024, 1024, 1024, nullptr);
    gemm_x3<0><<<dim3(64, 8), 256, 0, stream>>>(xn, 1024, in_proj_w + 1024 * 1024, 1024,
                                                zbuf, 1024, 1024, 1024, nullptr);
    conv_silu_kernel<<<dim3(NROWS, 4), 256, 0, stream>>>(xbuf, conv_w, conv_b, xc);
    gemm_x3<0><<<dim3(64, 1), 256, 0, stream>>>(xc, 1024, x_proj_w, 1024,
                                                dbl, 80, 80, 1024, nullptr);
    gemm_x3<1><<<dim3(64, 8), 256, 0, stream>>>(dbl, 80, dt_proj_w, 64,
                                                (void*)dth, 1024, 1024, 64, dt_proj_b);
    scan1_kernel<<<dim3(4, NCHUNK, 4), 256, 0, stream>>>(dth, xc, dbl, A_log, hF, Pb);
    scan_combine_kernel<<<dim3(16), 256, 0, stream>>>(hF, Pb, h0);
    scan2_kernel<<<dim3(4, NCHUNK, 4), 256, 0, stream>>>(dth, xc, dbl, A_log, h0,
                                                         zbuf, D_skip, yb);
    gemm_x3<0><<<dim3(64, 8), 256, 0, stream>>>(yb, 1024, out_proj_w, 1024,
                                                out, 1024, 1024, 1024, nullptr);
}

// Round 4
// 370.922 us; speedup vs baseline: 1.5231x; 1.5231x over previous
//
#include <hip/hip_runtime.h>
#include <stdint.h>
#include <stddef.h>

// Mamba block, B=4 L=2048 D=DI=1024 N=8 K=4 R=64. I/O fp32; GEMMs fp16 MFMA
// (operands pre-converted to fp16 in ws), m97-style global_load_lds staging.
// ws layout (MiB):
//   [0,16)   xn_h fp16 (rmsnorm out) -> reused as y_h (scan2 out)
//   [16,32)  xbuf_h fp16 (in_proj x half)
//   [32,48)  zbuf_h fp16 (in_proj z half)
//   [48,64)  xc_h fp16 (conv+silu out)
//   [64,68)  wih  (in_proj_w fp16 2048x1024)
//   [68,70)  woh  (out_proj_w fp16 1024x1024)
//   [70,70.5) wxh (x_proj_w fp16 80x1024)   [70.5,71) wdh (dt_proj_w fp16 1024x64)
//   [71,73.5) dbl_f fp32 [8192,80] (atomic accum)
//   [74,75)  dt_in fp16 [8192,64]
//   [75,91)  dth fp16 [8192,1024] (softplus dt)
//   [91,95) hF  [95,99) Pb  [99,103) h0   (fp32, NCHUNK=32)
// WS_NEED = 104 MiB (ws known >= 137 MiB from round-2 sentinel not firing).

typedef unsigned short u16;
typedef unsigned int u32;
typedef _Float16 f16;
typedef __attribute__((ext_vector_type(8))) _Float16 half8;
typedef __attribute__((ext_vector_type(4))) _Float16 half4;
typedef __attribute__((ext_vector_type(4))) float f32x4;

#define LSEQ 2048
#define DMODEL 1024
#define NSTATE 8
#define NCHUNK 32
#define CHUNKL 64
#define NROWS 8192
#define WS_NEED (104ull << 20)

__device__ __forceinline__ void gload_lds16(const void* g, void* l) {
    __builtin_amdgcn_global_load_lds((__attribute__((address_space(1))) void*)g,
                                     (__attribute__((address_space(3))) void*)l,
                                     16, 0, 0);
}

// diagnostic: ws too small -> unmistakable finite absmax (~999)
__global__ __launch_bounds__(256) void sentinel_kernel(float* __restrict__ out, int n) {
    int i = blockIdx.x * 256 + threadIdx.x;
    if (i < n) out[i] = 999.0f;
}

// ---- weight fp32->fp16 conversion, 4 tensors fused (sizes in elems/4) -----
#define T0 524288   // in_proj_w 2097152/4
#define T1 20480    // x_proj_w 81920/4
#define T2 16384    // dt_proj_w 65536/4
#define T3 262144   // out_proj_w 1048576/4
__global__ __launch_bounds__(256) void wcvt_kernel(const float* __restrict__ s0,
                                                   const float* __restrict__ s1,
                                                   const float* __restrict__ s2,
                                                   const float* __restrict__ s3,
                                                   f16* __restrict__ d0, f16* __restrict__ d1,
                                                   f16* __restrict__ d2, f16* __restrict__ d3) {
    int idx = blockIdx.x * 256 + threadIdx.x;
    const float* s; f16* d; int i;
    if (idx < T0) { s = s0; d = d0; i = idx; }
    else if (idx < T0 + T1) { s = s1; d = d1; i = idx - T0; }
    else if (idx < T0 + T1 + T2) { s = s2; d = d2; i = idx - T0 - T1; }
    else { s = s3; d = d3; i = idx - T0 - T1 - T2; }
    f32x4 v = *(const f32x4*)(s + (size_t)i * 4);
    half4 o; o[0] = (f16)v[0]; o[1] = (f16)v[1]; o[2] = (f16)v[2]; o[3] = (f16)v[3];
    *(half4*)(d + (size_t)i * 4) = o;
}

// ---------------- RMSNorm fp32 in -> fp16 out ----------------
__global__ __launch_bounds__(256) void rmsnorm_kernel(const float* __restrict__ X,
                                                      const float* __restrict__ W,
                                                      f16* __restrict__ O) {
    const int row = blockIdx.x;
    const int tid = threadIdx.x;
    f32x4 u = *(const f32x4*)(X + (size_t)row * DMODEL + tid * 4);
    float ss = u[0]*u[0] + u[1]*u[1] + u[2]*u[2] + u[3]*u[3];
    for (int off = 32; off; off >>= 1) ss += __shfl_down(ss, off, 64);
    __shared__ float red[4];
    if ((tid & 63) == 0) red[tid >> 6] = ss;
    __syncthreads();
    float tot = red[0] + red[1] + red[2] + red[3];
    float scale = rsqrtf(tot * (1.0f / DMODEL) + 1e-5f);
    f32x4 w = *(const f32x4*)(W + tid * 4);
    half4 o;
    o[0] = (f16)(u[0] * scale * w[0]); o[1] = (f16)(u[1] * scale * w[1]);
    o[2] = (f16)(u[2] * scale * w[2]); o[3] = (f16)(u[3] * scale * w[3]);
    *(half4*)(O + (size_t)row * DMODEL + tid * 4) = o;
}

// ---- fp16 GEMM (B^T): C[m,n] = sum_k A[m,k]*Bm[n,k], global_load_lds ------
// tile 128x128, BK=64, 256 thr (4 waves 2x2), mfma_f32_16x16x32_f16.
// EPI 0: split fp16 store (col<1024 -> C0, else C1). EPI 1: fp32 store C0.
// EPI 2: atomicAdd fp32 C0. EPI 3: fp16 softplus(acc+fbias[n]) -> C0.
template <int EPI>
__global__ __launch_bounds__(256) void gemm_f16(const f16* __restrict__ A, int lda,
                                                const f16* __restrict__ Bm, int ldb,
                                                void* __restrict__ C0, void* __restrict__ C1,
                                                int ldc, int N, int klen,
                                                const float* __restrict__ fbias) {
    __shared__ alignas(16) f16 sA[128 * 64];
    __shared__ alignas(16) f16 sB[128 * 64];
    const int tid = threadIdx.x;
    const int wave = tid >> 6, lane = tid & 63;
    const int wm = (wave >> 1) * 64, wn = (wave & 1) * 64;
    const int tm = blockIdx.x, tn = blockIdx.y;
    const int q = lane >> 4, cl = lane & 15;
    const int kbeg = blockIdx.z * klen;

    f32x4 acc[4][4];
    const f32x4 zero4 = {0.f, 0.f, 0.f, 0.f};
#pragma unroll
    for (int t = 0; t < 4; t++)
#pragma unroll
        for (int u = 0; u < 4; u++) acc[t][u] = zero4;

    // chunk assignment: c = wave*256 + j*64 + lane covers 0..1023 exactly.
    // LDS slot c holds global k-chunk gk = (c&7) ^ ((c>>3)&7) of row c>>3.
    int rS[4], gkS[4];
#pragma unroll
    for (int j = 0; j < 4; j++) {
        int c = wave * 256 + j * 64 + lane;
        rS[j] = c >> 3;
        gkS[j] = (c & 7) ^ (rS[j] & 7);
    }

    for (int k0 = kbeg; k0 < kbeg + klen; k0 += 64) {
        __syncthreads();   // prev iter's fragment reads complete
#pragma unroll
        for (int j = 0; j < 4; j++) {
            int ldsoff = (wave * 256 + j * 64) * 8;   // wave-uniform base
            int ga = tm * 128 + rS[j];
            gload_lds16(A + (size_t)ga * lda + k0 + gkS[j] * 8, sA + ldsoff);
            int gb = tn * 128 + rS[j];
            if (gb >= N) gb = N - 1;   // clamp; garbage cols never stored
            gload_lds16(Bm + (size_t)gb * ldb + k0 + gkS[j] * 8, sB + ldsoff);
        }
        __syncthreads();   // drains vmcnt -> LDS visible

        half8 af[4][2], bf[4][2];
#pragma unroll
        for (int t = 0; t < 4; t++)
#pragma unroll
            for (int s = 0; s < 2; s++) {
                int m = wm + t * 16 + cl;
                int kc = s * 4 + q;
                af[t][s] = *(const half8*)(sA + m * 64 + ((kc ^ (m & 7)) << 3));
                int n = wn + t * 16 + cl;
                bf[t][s] = *(const half8*)(sB + n * 64 + ((kc ^ (n & 7)) << 3));
            }
#pragma unroll
        for (int t = 0; t < 4; t++)
#pragma unroll
            for (int u = 0; u < 4; u++) {
                acc[t][u] = __builtin_amdgcn_mfma_f32_16x16x32_f16(af[t][0], bf[u][0], acc[t][u], 0, 0, 0);
                acc[t][u] = __builtin_amdgcn_mfma_f32_16x16x32_f16(af[t][1], bf[u][1], acc[t][u], 0, 0, 0);
            }
    }

    const int rowbase = tm * 128 + wm + q * 4;
    const int colbase = tn * 128 + wn + cl;
#pragma unroll
    for (int t = 0; t < 4; t++)
#pragma unroll
        for (int r = 0; r < 4; r++) {
            size_t rb_ = (size_t)(rowbase + t * 16 + r) * ldc;
            size_t rb1 = (size_t)(rowbase + t * 16 + r) * 1024;
#pragma unroll
            for (int u = 0; u < 4; u++) {
                int gcol = colbase + u * 16;
                float v = acc[t][u][r];
                if (EPI == 0) {
                    if (gcol < 1024) ((f16*)C0)[rb1 + gcol] = (f16)v;
                    else             ((f16*)C1)[rb1 + gcol - 1024] = (f16)v;
                } else if (EPI == 1) {
                    if (gcol < N) ((float*)C0)[rb_ + gcol] = v;
                } else if (EPI == 2) {
                    if (gcol < N) atomicAdd((float*)C0 + rb_ + gcol, v);
                } else {
                    if (gcol < N) {
                        float sv = v + fbias[gcol];
                        sv = (sv > 15.f) ? sv : log1pf(__expf(sv));
                        ((f16*)C0)[rb_ + gcol] = (f16)sv;
                    }
                }
            }
        }
}

// ------------- causal depthwise conv (K=4) + bias + silu, fp16 io -----------
__global__ __launch_bounds__(256) void conv_silu_kernel(const f16* __restrict__ x,
                                                        const float* __restrict__ cw,
                                                        const float* __restrict__ cb,
                                                        f16* __restrict__ xc) {
    const int row = blockIdx.x;                 // b*2048 + l
    const int d = blockIdx.y * 256 + threadIdx.x;
    const int l = row & (LSEQ - 1);
    float acc = cb[d];
#pragma unroll
    for (int j = 0; j < 4; j++) {
        int ll = l - 3 + j;
        if (ll >= 0)
            acc += cw[d * 4 + j] * (float)x[(size_t)(row - 3 + j) * 1024 + d];
    }
    xc[(size_t)row * 1024 + d] = (f16)(acc / (1.f + __expf(-acc)));
}

// ---- dbl_f[:, :64] fp32 -> dt_in fp16 (A of dt_proj) ----
__global__ __launch_bounds__(256) void dtin_kernel(const float* __restrict__ dbl,
                                                   f16* __restrict__ dt_in) {
    int idx = blockIdx.x * 256 + threadIdx.x;    // 131072 threads, 4 elems each
    int row = idx >> 4, j4 = (idx & 15) * 4;
    f32x4 v = *(const f32x4*)(dbl + (size_t)row * 80 + j4);
    half4 o; o[0] = (f16)v[0]; o[1] = (f16)v[1]; o[2] = (f16)v[2]; o[3] = (f16)v[3];
    *(half4*)(dt_in + (size_t)row * 64 + j4) = o;
}

// ---------------- selective scan, chunked (32 chunks of 64) -----------------
__global__ __launch_bounds__(256) void scan1_kernel(const f16* __restrict__ dt,
                                                    const f16* __restrict__ xc,
                                                    const float* __restrict__ dbl,
                                                    const float* __restrict__ A_log,
                                                    float* __restrict__ hF,
                                                    float* __restrict__ Pb) {
    const int d = blockIdx.x * 256 + threadIdx.x;
    const int c = blockIdx.y;
    const int b = blockIdx.z;
    __shared__ float sB[CHUNKL * NSTATE];
    for (int i = threadIdx.x; i < CHUNKL * NSTATE; i += 256)
        sB[i] = dbl[(size_t)(b * LSEQ + c * CHUNKL + (i >> 3)) * 80 + 64 + (i & 7)];
    __syncthreads();
    float Aa[NSTATE];
#pragma unroll
    for (int n = 0; n < NSTATE; n++) Aa[n] = -__expf(A_log[d * NSTATE + n]);
    float h[NSTATE], P[NSTATE];
#pragma unroll
    for (int n = 0; n < NSTATE; n++) { h[n] = 0.f; P[n] = 1.f; }
    for (int li = 0; li < CHUNKL; li++) {
        size_t rowb = (size_t)(b * LSEQ + c * CHUNKL + li);
        float dtv = (float)dt[rowb * 1024 + d];
        float xv = (float)xc[rowb * 1024 + d];
        float dtx = dtv * xv;
#pragma unroll
        for (int n = 0; n < NSTATE; n++) {
            float e = __expf(Aa[n] * dtv);
            h[n] = e * h[n] + dtx * sB[li * 8 + n];
            P[n] *= e;
        }
    }
    size_t base = ((size_t)(b * 1024 + d) * NCHUNK + c) * NSTATE;
#pragma unroll
    for (int n = 0; n < NSTATE; n++) { hF[base + n] = h[n]; Pb[base + n] = P[n]; }
}

__global__ __launch_bounds__(256) void scan_combine_kernel(const float* __restrict__ hF,
                                                           const float* __restrict__ Pb,
                                                           float* __restrict__ h0) {
    const int idx = blockIdx.x * 256 + threadIdx.x;   // b*1024+d
    float carry[NSTATE];
#pragma unroll
    for (int n = 0; n < NSTATE; n++) carry[n] = 0.f;
    for (int c = 0; c < NCHUNK; c++) {
        size_t base = ((size_t)idx * NCHUNK + c) * NSTATE;
#pragma unroll
        for (int n = 0; n < NSTATE; n++) {
            h0[base + n] = carry[n];
            carry[n] = Pb[base + n] * carry[n] + hF[base + n];
        }
    }
}

__global__ __launch_bounds__(256) void scan2_kernel(const f16* __restrict__ dt,
                                                    const f16* __restrict__ xc,
                                                    const float* __restrict__ dbl,
                                                    const float* __restrict__ A_log,
                                                    const float* __restrict__ h0,
                                                    const f16* __restrict__ z,
                                                    const float* __restrict__ Dsk,
                                                    f16* __restrict__ yout) {
    const int d = blockIdx.x * 256 + threadIdx.x;
    const int c = blockIdx.y;
    const int b = blockIdx.z;
    __shared__ float sB[CHUNKL * NSTATE];
    __shared__ float sC[CHUNKL * NSTATE];
    for (int i = threadIdx.x; i < CHUNKL * NSTATE; i += 256) {
        size_t rb = (size_t)(b * LSEQ + c * CHUNKL + (i >> 3)) * 80;
        sB[i] = dbl[rb + 64 + (i & 7)];
        sC[i] = dbl[rb + 72 + (i & 7)];
    }
    __syncthreads();
    float Aa[NSTATE];
#pragma unroll
    for (int n = 0; n < NSTATE; n++) Aa[n] = -__expf(A_log[d * NSTATE + n]);
    float h[NSTATE];
    {
        size_t base = ((size_t)(b * 1024 + d) * NCHUNK + c) * NSTATE;
#pragma unroll
        for (int n = 0; n < NSTATE; n++) h[n] = h0[base + n];
    }
    const float dval = Dsk[d];
    for (int li = 0; li < CHUNKL; li++) {
        size_t rowb = (size_t)(b * LSEQ + c * CHUNKL + li);
        float dtv = (float)dt[rowb * 1024 + d];
        float xv = (float)xc[rowb * 1024 + d];
        float dtx = dtv * xv;
        float y = 0.f;
#pragma unroll
        for (int n = 0; n < NSTATE; n++) {
            float e = __expf(Aa[n] * dtv);
            h[n] = e * h[n] + dtx * sB[li * 8 + n];
            y += h[n] * sC[li * 8 + n];
        }
        y += dval * xv;
        float zv = (float)z[rowb * 1024 + d];
        y *= zv / (1.f + __expf(-zv));
        yout[rowb * 1024 + d] = (f16)y;
    }
}

extern "C" void kernel_launch(void* const* d_in, const int* in_sizes, int n_in,
                              void* d_out, int out_size, void* d_ws, size_t ws_size,
                              hipStream_t stream) {
    (void)in_sizes; (void)n_in;
    const float* hidden    = (const float*)d_in[0];
    const float* norm_w    = (const float*)d_in[1];
    const float* in_proj_w = (const float*)d_in[2];
    const float* conv_w    = (const float*)d_in[3];
    const float* conv_b    = (const float*)d_in[4];
    const float* x_proj_w  = (const float*)d_in[5];
    const float* dt_proj_w = (const float*)d_in[6];
    const float* dt_proj_b = (const float*)d_in[7];
    const float* A_log     = (const float*)d_in[8];
    const float* D_skip    = (const float*)d_in[9];
    const float* out_proj_w= (const float*)d_in[10];
    float* out = (float*)d_out;

    if (ws_size < WS_NEED) {
        sentinel_kernel<<<dim3((out_size + 255) / 256), 256, 0, stream>>>(out, out_size);
        return;
    }

    char* ws = (char*)d_ws;
    f16*   xn_h  = (f16*)(ws);                         // [0,16) -> y_h later
    f16*   xbuf_h= (f16*)(ws + (16ull << 20));         // [16,32)
    f16*   zbuf_h= (f16*)(ws + (32ull << 20));         // [32,48)
    f16*   xc_h  = (f16*)(ws + (48ull << 20));         // [48,64)
    f16*   wih   = (f16*)(ws + (64ull << 20));         // [64,68)
    f16*   woh   = (f16*)(ws + (68ull << 20));         // [68,70)
    f16*   wxh   = (f16*)(ws + (70ull << 20));         // 160 KB
    f16*   wdh   = (f16*)(ws + (70ull << 20) + (512ull << 10));  // 128 KB
    float* dbl_f = (float*)(ws + (71ull << 20));       // 2.5 MB
    f16*   dt_in = (f16*)(ws + (74ull << 20));         // 1 MB
    f16*   dth   = (f16*)(ws + (75ull << 20));         // [75,91)
    float* hF    = (float*)(ws + (91ull << 20));       // 4 MB
    float* Pb    = (float*)(ws + (95ull << 20));       // 4 MB
    float* h0    = (float*)(ws + (99ull << 20));       // 4 MB
    f16*   y_h   = xn_h;

    wcvt_kernel<<<dim3(3216), 256, 0, stream>>>(in_proj_w, x_proj_w, dt_proj_w, out_proj_w,
                                                wih, wxh, wdh, woh);
    rmsnorm_kernel<<<dim3(NROWS), 256, 0, stream>>>(hidden, norm_w, xn_h);
    // in_proj fused (N=2048): cols 0..1023 -> xbuf_h, 1024..2047 -> zbuf_h
    gemm_f16<0><<<dim3(64, 16), 256, 0, stream>>>(xn_h, 1024, wih, 1024,
                                                  xbuf_h, zbuf_h, 1024, 2048, 1024, nullptr);
    conv_silu_kernel<<<dim3(NROWS, 4), 256, 0, stream>>>(xbuf_h, conv_w, conv_b, xc_h);
    hipMemsetAsync(dbl_f, 0, (size_t)NROWS * 80 * sizeof(float), stream);
    // x_proj: K-split x4, atomic fp32 accumulate
    gemm_f16<2><<<dim3(64, 1, 4), 256, 0, stream>>>(xc_h, 1024, wxh, 1024,
                                                    dbl_f, nullptr, 80, 80, 256, nullptr);
    dtin_kernel<<<dim3(512), 256, 0, stream>>>(dbl_f, dt_in);
    // dt_proj: K=64 single iter, softplus epilogue -> dth fp16
    gemm_f16<3><<<dim3(64, 8), 256, 0, stream>>>(dt_in, 64, wdh, 64,
                                                 dth, nullptr, 1024, 1024, 64, dt_proj_b);
    scan1_kernel<<<dim3(4, NCHUNK, 4), 256, 0, stream>>>(dth, xc_h, dbl_f, A_log, hF, Pb);
    scan_combine_kernel<<<dim3(16), 256, 0, stream>>>(hF, Pb, h0);
    scan2_kernel<<<dim3(4, NCHUNK, 4), 256, 0, stream>>>(dth, xc_h, dbl_f, A_log, h0,
                                                         zbuf_h, D_skip, y_h);
    gemm_f16<1><<<dim3(64, 8), 256, 0, stream>>>(y_h, 1024, woh, 1024,
                                                 out, nullptr, 1024, 1024, 1024, nullptr);
}

// Round 5
// 332.123 us; speedup vs baseline: 1.7011x; 1.1168x over previous
//
#include <hip/hip_runtime.h>
#include <stdint.h>
#include <stddef.h>

// Mamba block, B=4 L=2048 D=DI=1024 N=8 K=4 R=64. I/O fp32; GEMMs fp16 MFMA,
// m97-style global_load_lds staging. 8 dispatches:
//   prep (wcvt + zero dbl + rmsnorm) -> in_proj -> conv -> x_proj(atomic K-split)
//   -> dt_proj (fp32-A convert, softplus) -> scan1 -> scan2 (inline chunk-prefix)
//   -> out_proj
// ws layout (MiB):
//   [0,16)   xn_h fp16 (rmsnorm out) -> reused as y_h (scan2 out)
//   [16,32)  xbuf_h fp16 (in_proj x half)
//   [32,48)  zbuf_h fp16 (in_proj z half)
//   [48,64)  xc_h fp16 (conv+silu out)
//   [64,68)  wih (in_proj_w fp16)   [68,70) woh (out_proj_w fp16)
//   [70,+160K) wxh (x_proj_w fp16)  [70.5,+128K) wdh (dt_proj_w fp16)
//   [71,73.5) dbl_f fp32 [8192,80] (atomic accum)
//   [75,91)  dth fp16 [8192,1024] (softplus dt)
//   [91,95)  hF   [95,99) Pb   (fp32, NCHUNK=32)
// WS_NEED = 99 MiB.

typedef unsigned short u16;
typedef unsigned int u32;
typedef _Float16 f16;
typedef __attribute__((ext_vector_type(8))) _Float16 half8;
typedef __attribute__((ext_vector_type(4))) _Float16 half4;
typedef __attribute__((ext_vector_type(4))) float f32x4;

#define LSEQ 2048
#define DMODEL 1024
#define NSTATE 8
#define NCHUNK 32
#define CHUNKL 64
#define NROWS 8192
#define WS_NEED (99ull << 20)

__device__ __forceinline__ void gload_lds16(const void* g, void* l) {
    __builtin_amdgcn_global_load_lds((__attribute__((address_space(1))) void*)g,
                                     (__attribute__((address_space(3))) void*)l,
                                     16, 0, 0);
}

__global__ __launch_bounds__(256) void sentinel_kernel(float* __restrict__ out, int n) {
    int i = blockIdx.x * 256 + threadIdx.x;
    if (i < n) out[i] = 999.0f;
}

// ---- prep: weight fp32->fp16 (4 tensors) + zero dbl_f + rmsnorm ----
#define T0 524288   // in_proj_w /4
#define T1 20480    // x_proj_w /4
#define T2 16384    // dt_proj_w /4
#define T3 262144   // out_proj_w /4
#define WCVT_BLK 3216          // (T0+T1+T2+T3)/256
#define ZERO_BLK 640           // 8192*80*4B / 16B / 256
__global__ __launch_bounds__(256) void prep_kernel(const float* __restrict__ s0,
                                                   const float* __restrict__ s1,
                                                   const float* __restrict__ s2,
                                                   const float* __restrict__ s3,
                                                   f16* __restrict__ d0, f16* __restrict__ d1,
                                                   f16* __restrict__ d2, f16* __restrict__ d3,
                                                   float* __restrict__ dblz,
                                                   const float* __restrict__ X,
                                                   const float* __restrict__ W,
                                                   f16* __restrict__ O) {
    const int bx = blockIdx.x;
    const int tid = threadIdx.x;
    if (bx < WCVT_BLK) {
        int idx = bx * 256 + tid;
        const float* s; f16* d; int i;
        if (idx < T0) { s = s0; d = d0; i = idx; }
        else if (idx < T0 + T1) { s = s1; d = d1; i = idx - T0; }
        else if (idx < T0 + T1 + T2) { s = s2; d = d2; i = idx - T0 - T1; }
        else { s = s3; d = d3; i = idx - T0 - T1 - T2; }
        f32x4 v = *(const f32x4*)(s + (size_t)i * 4);
        half4 o; o[0] = (f16)v[0]; o[1] = (f16)v[1]; o[2] = (f16)v[2]; o[3] = (f16)v[3];
        *(half4*)(d + (size_t)i * 4) = o;
    } else if (bx < WCVT_BLK + ZERO_BLK) {
        int i = (bx - WCVT_BLK) * 256 + tid;
        const f32x4 z4 = {0.f, 0.f, 0.f, 0.f};
        ((f32x4*)dblz)[i] = z4;
    } else {
        const int row = bx - (WCVT_BLK + ZERO_BLK);
        f32x4 u = *(const f32x4*)(X + (size_t)row * DMODEL + tid * 4);
        float ss = u[0]*u[0] + u[1]*u[1] + u[2]*u[2] + u[3]*u[3];
        for (int off = 32; off; off >>= 1) ss += __shfl_down(ss, off, 64);
        __shared__ float red[4];
        if ((tid & 63) == 0) red[tid >> 6] = ss;
        __syncthreads();
        float tot = red[0] + red[1] + red[2] + red[3];
        float scale = rsqrtf(tot * (1.0f / DMODEL) + 1e-5f);
        f32x4 w = *(const f32x4*)(W + tid * 4);
        half4 o;
        o[0] = (f16)(u[0] * scale * w[0]); o[1] = (f16)(u[1] * scale * w[1]);
        o[2] = (f16)(u[2] * scale * w[2]); o[3] = (f16)(u[3] * scale * w[3]);
        *(half4*)(O + (size_t)row * DMODEL + tid * 4) = o;
    }
}

// ---- fp16 GEMM (B^T): C[m,n] = sum_k A[m,k]*Bm[n,k] ------
// tile 128x128, BK=64, 256 thr (4 waves 2x2), mfma_f32_16x16x32_f16.
// AF32: A is fp32, fragments converted in-register (no LDS for A).
// EPI 0: split fp16 store (col<1024 -> C0, else C1). EPI 1: fp32 store C0.
// EPI 2: atomicAdd fp32 C0. EPI 3: fp16 softplus(acc+fbias[n]) -> C0.
template <int EPI, int AF32>
__global__ __launch_bounds__(256) void gemm_f16(const void* __restrict__ Ap, int lda,
                                                const f16* __restrict__ Bm, int ldb,
                                                void* __restrict__ C0, void* __restrict__ C1,
                                                int ldc, int N, int klen,
                                                const float* __restrict__ fbias) {
    __shared__ alignas(16) f16 sA[128 * 64];
    __shared__ alignas(16) f16 sB[128 * 64];
    const int tid = threadIdx.x;
    const int wave = tid >> 6, lane = tid & 63;
    const int wm = (wave >> 1) * 64, wn = (wave & 1) * 64;
    const int tm = blockIdx.x, tn = blockIdx.y;
    const int q = lane >> 4, cl = lane & 15;
    const int kbeg = blockIdx.z * klen;

    f32x4 acc[4][4];
    const f32x4 zero4 = {0.f, 0.f, 0.f, 0.f};
#pragma unroll
    for (int t = 0; t < 4; t++)
#pragma unroll
        for (int u = 0; u < 4; u++) acc[t][u] = zero4;

    int rS[4], gkS[4];
#pragma unroll
    for (int j = 0; j < 4; j++) {
        int c = wave * 256 + j * 64 + lane;
        rS[j] = c >> 3;
        gkS[j] = (c & 7) ^ (rS[j] & 7);
    }

    for (int k0 = kbeg; k0 < kbeg + klen; k0 += 64) {
        __syncthreads();   // prev iter's fragment reads complete
#pragma unroll
        for (int j = 0; j < 4; j++) {
            int ldsoff = (wave * 256 + j * 64) * 8;   // wave-uniform base
            if (!AF32) {
                int ga = tm * 128 + rS[j];
                gload_lds16((const f16*)Ap + (size_t)ga * lda + k0 + gkS[j] * 8, sA + ldsoff);
            }
            int gb = tn * 128 + rS[j];
            if (gb >= N) gb = N - 1;   // clamp; garbage cols never stored
            gload_lds16(Bm + (size_t)gb * ldb + k0 + gkS[j] * 8, sB + ldsoff);
        }
        __syncthreads();   // drains vmcnt -> LDS visible

        half8 af[4][2], bf[4][2];
#pragma unroll
        for (int t = 0; t < 4; t++)
#pragma unroll
            for (int s = 0; s < 2; s++) {
                int m = wm + t * 16 + cl;
                int kc = s * 4 + q;
                if (AF32) {
                    const float* pa = (const float*)Ap + (size_t)(tm * 128 + m) * lda + k0 + kc * 8;
                    f32x4 v0 = *(const f32x4*)pa, v1 = *(const f32x4*)(pa + 4);
                    half8 a;
                    a[0] = (f16)v0[0]; a[1] = (f16)v0[1]; a[2] = (f16)v0[2]; a[3] = (f16)v0[3];
                    a[4] = (f16)v1[0]; a[5] = (f16)v1[1]; a[6] = (f16)v1[2]; a[7] = (f16)v1[3];
                    af[t][s] = a;
                } else {
                    af[t][s] = *(const half8*)(sA + m * 64 + ((kc ^ (m & 7)) << 3));
                }
                int n = wn + t * 16 + cl;
                bf[t][s] = *(const half8*)(sB + n * 64 + ((kc ^ (n & 7)) << 3));
            }
#pragma unroll
        for (int t = 0; t < 4; t++)
#pragma unroll
            for (int u = 0; u < 4; u++) {
                acc[t][u] = __builtin_amdgcn_mfma_f32_16x16x32_f16(af[t][0], bf[u][0], acc[t][u], 0, 0, 0);
                acc[t][u] = __builtin_amdgcn_mfma_f32_16x16x32_f16(af[t][1], bf[u][1], acc[t][u], 0, 0, 0);
            }
    }

    const int rowbase = tm * 128 + wm + q * 4;
    const int colbase = tn * 128 + wn + cl;
#pragma unroll
    for (int t = 0; t < 4; t++)
#pragma unroll
        for (int r = 0; r < 4; r++) {
            size_t rb_ = (size_t)(rowbase + t * 16 + r) * ldc;
            size_t rb1 = (size_t)(rowbase + t * 16 + r) * 1024;
#pragma unroll
            for (int u = 0; u < 4; u++) {
                int gcol = colbase + u * 16;
                float v = acc[t][u][r];
                if (EPI == 0) {
                    if (gcol < 1024) ((f16*)C0)[rb1 + gcol] = (f16)v;
                    else             ((f16*)C1)[rb1 + gcol - 1024] = (f16)v;
                } else if (EPI == 1) {
                    if (gcol < N) ((float*)C0)[rb_ + gcol] = v;
                } else if (EPI == 2) {
                    if (gcol < N) atomicAdd((float*)C0 + rb_ + gcol, v);
                } else {
                    if (gcol < N) {
                        float sv = v + fbias[gcol];
                        sv = (sv > 15.f) ? sv : log1pf(__expf(sv));
                        ((f16*)C0)[rb_ + gcol] = (f16)sv;
                    }
                }
            }
        }
}

// ------- causal depthwise conv (K=4) + bias + silu, 4 rows per thread -------
__global__ __launch_bounds__(256) void conv_silu_kernel(const f16* __restrict__ x,
                                                        const float* __restrict__ cw,
                                                        const float* __restrict__ cb,
                                                        f16* __restrict__ xc) {
    const int rg = blockIdx.x;                  // row group: rows rg*4 .. rg*4+3
    const int d = blockIdx.y * 256 + threadIdx.x;
    const int row0 = rg * 4;
    const int l0 = row0 & (LSEQ - 1);
    float w0 = cw[d * 4], w1 = cw[d * 4 + 1], w2 = cw[d * 4 + 2], w3 = cw[d * 4 + 3];
    float bias = cb[d];
    float v[7];
#pragma unroll
    for (int j = 0; j < 7; j++) {
        int ll = l0 - 3 + j;
        v[j] = (ll >= 0) ? (float)x[(size_t)(row0 - 3 + j) * 1024 + d] : 0.f;
    }
#pragma unroll
    for (int i = 0; i < 4; i++) {
        float acc = bias + w0 * v[i] + w1 * v[i + 1] + w2 * v[i + 2] + w3 * v[i + 3];
        xc[(size_t)(row0 + i) * 1024 + d] = (f16)(acc / (1.f + __expf(-acc)));
    }
}

// ---------------- selective scan, chunked (32 chunks of 64) -----------------
__global__ __launch_bounds__(256) void scan1_kernel(const f16* __restrict__ dt,
                                                    const f16* __restrict__ xc,
                                                    const float* __restrict__ dbl,
                                                    const float* __restrict__ A_log,
                                                    float* __restrict__ hF,
                                                    float* __restrict__ Pb) {
    const int d = blockIdx.x * 256 + threadIdx.x;
    const int c = blockIdx.y;
    const int b = blockIdx.z;
    __shared__ float sB[CHUNKL * NSTATE];
    for (int i = threadIdx.x; i < CHUNKL * NSTATE; i += 256)
        sB[i] = dbl[(size_t)(b * LSEQ + c * CHUNKL + (i >> 3)) * 80 + 64 + (i & 7)];
    __syncthreads();
    float Aa[NSTATE];
#pragma unroll
    for (int n = 0; n < NSTATE; n++) Aa[n] = -__expf(A_log[d * NSTATE + n]);
    float h[NSTATE], P[NSTATE];
#pragma unroll
    for (int n = 0; n < NSTATE; n++) { h[n] = 0.f; P[n] = 1.f; }
    for (int li = 0; li < CHUNKL; li++) {
        size_t rowb = (size_t)(b * LSEQ + c * CHUNKL + li);
        float dtv = (float)dt[rowb * 1024 + d];
        float xv = (float)xc[rowb * 1024 + d];
        float dtx = dtv * xv;
#pragma unroll
        for (int n = 0; n < NSTATE; n++) {
            float e = __expf(Aa[n] * dtv);
            h[n] = e * h[n] + dtx * sB[li * 8 + n];
            P[n] *= e;
        }
    }
    size_t base = ((size_t)(b * 1024 + d) * NCHUNK + c) * NSTATE;
#pragma unroll
    for (int n = 0; n < NSTATE; n++) { hF[base + n] = h[n]; Pb[base + n] = P[n]; }
}

// pass 2 with inlined chunk-prefix combine (h0 computed from hF/Pb)
__global__ __launch_bounds__(256) void scan2_kernel(const f16* __restrict__ dt,
                                                    const f16* __restrict__ xc,
                                                    const float* __restrict__ dbl,
                                                    const float* __restrict__ A_log,
                                                    const float* __restrict__ hF,
                                                    const float* __restrict__ Pb,
                                                    const f16* __restrict__ z,
                                                    const float* __restrict__ Dsk,
                                                    f16* __restrict__ yout) {
    const int d = blockIdx.x * 256 + threadIdx.x;
    const int c = blockIdx.y;
    const int b = blockIdx.z;
    __shared__ float sB[CHUNKL * NSTATE];
    __shared__ float sC[CHUNKL * NSTATE];
    for (int i = threadIdx.x; i < CHUNKL * NSTATE; i += 256) {
        size_t rb = (size_t)(b * LSEQ + c * CHUNKL + (i >> 3)) * 80;
        sB[i] = dbl[rb + 64 + (i & 7)];
        sC[i] = dbl[rb + 72 + (i & 7)];
    }
    __syncthreads();
    float Aa[NSTATE];
#pragma unroll
    for (int n = 0; n < NSTATE; n++) Aa[n] = -__expf(A_log[d * NSTATE + n]);
    // inline combine: h = prefix state entering chunk c
    float h[NSTATE];
#pragma unroll
    for (int n = 0; n < NSTATE; n++) h[n] = 0.f;
    {
        size_t dbase = (size_t)(b * 1024 + d) * NCHUNK * NSTATE;
        for (int cc = 0; cc < c; cc++) {
            size_t base = dbase + (size_t)cc * NSTATE;
#pragma unroll
            for (int n = 0; n < NSTATE; n++)
                h[n] = Pb[base + n] * h[n] + hF[base + n];
        }
    }
    const float dval = Dsk[d];
    for (int li = 0; li < CHUNKL; li++) {
        size_t rowb = (size_t)(b * LSEQ + c * CHUNKL + li);
        float dtv = (float)dt[rowb * 1024 + d];
        float xv = (float)xc[rowb * 1024 + d];
        float dtx = dtv * xv;
        float y = 0.f;
#pragma unroll
        for (int n = 0; n < NSTATE; n++) {
            float e = __expf(Aa[n] * dtv);
            h[n] = e * h[n] + dtx * sB[li * 8 + n];
            y += h[n] * sC[li * 8 + n];
        }
        y += dval * xv;
        float zv = (float)z[rowb * 1024 + d];
        y *= zv / (1.f + __expf(-zv));
        yout[rowb * 1024 + d] = (f16)y;
    }
}

extern "C" void kernel_launch(void* const* d_in, const int* in_sizes, int n_in,
                              void* d_out, int out_size, void* d_ws, size_t ws_size,
                              hipStream_t stream) {
    (void)in_sizes; (void)n_in;
    const float* hidden    = (const float*)d_in[0];
    const float* norm_w    = (const float*)d_in[1];
    const float* in_proj_w = (const float*)d_in[2];
    const float* conv_w    = (const float*)d_in[3];
    const float* conv_b    = (const float*)d_in[4];
    const float* x_proj_w  = (const float*)d_in[5];
    const float* dt_proj_w = (const float*)d_in[6];
    const float* dt_proj_b = (const float*)d_in[7];
    const float* A_log     = (const float*)d_in[8];
    const float* D_skip    = (const float*)d_in[9];
    const float* out_proj_w= (const float*)d_in[10];
    float* out = (float*)d_out;

    if (ws_size < WS_NEED) {
        sentinel_kernel<<<dim3((out_size + 255) / 256), 256, 0, stream>>>(out, out_size);
        return;
    }

    char* ws = (char*)d_ws;
    f16*   xn_h  = (f16*)(ws);                         // [0,16) -> y_h later
    f16*   xbuf_h= (f16*)(ws + (16ull << 20));         // [16,32)
    f16*   zbuf_h= (f16*)(ws + (32ull << 20));         // [32,48)
    f16*   xc_h  = (f16*)(ws + (48ull << 20));         // [48,64)
    f16*   wih   = (f16*)(ws + (64ull << 20));         // [64,68)
    f16*   woh   = (f16*)(ws + (68ull << 20));         // [68,70)
    f16*   wxh   = (f16*)(ws + (70ull << 20));         // 160 KB
    f16*   wdh   = (f16*)(ws + (70ull << 20) + (512ull << 10));  // 128 KB
    float* dbl_f = (float*)(ws + (71ull << 20));       // 2.5 MB
    f16*   dth   = (f16*)(ws + (75ull << 20));         // [75,91)
    float* hF    = (float*)(ws + (91ull << 20));       // 4 MB
    float* Pb    = (float*)(ws + (95ull << 20));       // 4 MB
    f16*   y_h   = xn_h;

    prep_kernel<<<dim3(WCVT_BLK + ZERO_BLK + NROWS), 256, 0, stream>>>(
        in_proj_w, x_proj_w, dt_proj_w, out_proj_w, wih, wxh, wdh, woh,
        dbl_f, hidden, norm_w, xn_h);
    // in_proj fused (N=2048): cols 0..1023 -> xbuf_h, 1024..2047 -> zbuf_h
    gemm_f16<0, 0><<<dim3(64, 16), 256, 0, stream>>>(xn_h, 1024, wih, 1024,
                                                     xbuf_h, zbuf_h, 1024, 2048, 1024, nullptr);
    conv_silu_kernel<<<dim3(NROWS / 4, 4), 256, 0, stream>>>(xbuf_h, conv_w, conv_b, xc_h);
    // x_proj: K-split x4, atomic fp32 accumulate into dbl_f (zeroed by prep)
    gemm_f16<2, 0><<<dim3(64, 1, 4), 256, 0, stream>>>(xc_h, 1024, wxh, 1024,
                                                       dbl_f, nullptr, 80, 80, 256, nullptr);
    // dt_proj: fp32 A (dbl_f cols 0..63), K=64, softplus epilogue -> dth fp16
    gemm_f16<3, 1><<<dim3(64, 8), 256, 0, stream>>>(dbl_f, 80, wdh, 64,
                                                    dth, nullptr, 1024, 1024, 64, dt_proj_b);
    scan1_kernel<<<dim3(4, NCHUNK, 4), 256, 0, stream>>>(dth, xc_h, dbl_f, A_log, hF, Pb);
    scan2_kernel<<<dim3(4, NCHUNK, 4), 256, 0, stream>>>(dth, xc_h, dbl_f, A_log, hF, Pb,
                                                         zbuf_h, D_skip, y_h);
    gemm_f16<1, 0><<<dim3(64, 8), 256, 0, stream>>>(y_h, 1024, woh, 1024,
                                                    out, nullptr, 1024, 1024, 1024, nullptr);
}

// Round 6
// 295.778 us; speedup vs baseline: 1.9101x; 1.1229x over previous
//
#include <hip/hip_runtime.h>
#include <stdint.h>
#include <stddef.h>

// Mamba block, B=4 L=2048 D=DI=1024 N=8 K=4 R=64. I/O fp32; GEMMs fp16 MFMA,
// m97-style global_load_lds staging. 9 dispatches:
//   prep (wcvt + zero dbl + rmsnorm) -> in_proj -> conv -> x_proj(atomic K-split)
//   -> dt_proj (fp32-A) -> scan1 -> combine -> scan2 -> out_proj
// Scan: NCHUNK=64 chunks of 32, chunk-major state [c][b][d][n], batched loads.
// ws layout (MiB):
//   [0,16)   xn_h fp16 (rmsnorm out) -> reused as y_h (scan2 out)
//   [16,32)  xbuf_h   [32,48) zbuf_h   [48,64) xc_h
//   [64,68)  wih   [68,70) woh   [70,+160K) wxh   [70.5,+128K) wdh
//   [71,73.5) dbl_f fp32 [8192,80]
//   [75,91)  dth fp16 [8192,1024]
//   [91,99)  hF   [99,107) Pb   [107,115) h0   (fp32, chunk-major)
// WS_NEED = 115 MiB (ws_size >= 137 MiB proven by round-2 pass).

typedef unsigned short u16;
typedef unsigned int u32;
typedef _Float16 f16;
typedef __attribute__((ext_vector_type(8))) _Float16 half8;
typedef __attribute__((ext_vector_type(4))) _Float16 half4;
typedef __attribute__((ext_vector_type(4))) float f32x4;

#define LSEQ 2048
#define DMODEL 1024
#define NSTATE 8
#define NCHUNK 64
#define CHUNKL 32
#define NROWS 8192
#define WS_NEED (115ull << 20)

__device__ __forceinline__ void gload_lds16(const void* g, void* l) {
    __builtin_amdgcn_global_load_lds((__attribute__((address_space(1))) void*)g,
                                     (__attribute__((address_space(3))) void*)l,
                                     16, 0, 0);
}

__global__ __launch_bounds__(256) void sentinel_kernel(float* __restrict__ out, int n) {
    int i = blockIdx.x * 256 + threadIdx.x;
    if (i < n) out[i] = 999.0f;
}

// ---- prep: weight fp32->fp16 (4 tensors) + zero dbl_f + rmsnorm ----
#define T0 524288   // in_proj_w /4
#define T1 20480    // x_proj_w /4
#define T2 16384    // dt_proj_w /4
#define T3 262144   // out_proj_w /4
#define WCVT_BLK 3216          // (T0+T1+T2+T3)/256
#define ZERO_BLK 640           // 8192*80*4B / 16B / 256
__global__ __launch_bounds__(256) void prep_kernel(const float* __restrict__ s0,
                                                   const float* __restrict__ s1,
                                                   const float* __restrict__ s2,
                                                   const float* __restrict__ s3,
                                                   f16* __restrict__ d0, f16* __restrict__ d1,
                                                   f16* __restrict__ d2, f16* __restrict__ d3,
                                                   float* __restrict__ dblz,
                                                   const float* __restrict__ X,
                                                   const float* __restrict__ W,
                                                   f16* __restrict__ O) {
    const int bx = blockIdx.x;
    const int tid = threadIdx.x;
    if (bx < WCVT_BLK) {
        int idx = bx * 256 + tid;
        const float* s; f16* d; int i;
        if (idx < T0) { s = s0; d = d0; i = idx; }
        else if (idx < T0 + T1) { s = s1; d = d1; i = idx - T0; }
        else if (idx < T0 + T1 + T2) { s = s2; d = d2; i = idx - T0 - T1; }
        else { s = s3; d = d3; i = idx - T0 - T1 - T2; }
        f32x4 v = *(const f32x4*)(s + (size_t)i * 4);
        half4 o; o[0] = (f16)v[0]; o[1] = (f16)v[1]; o[2] = (f16)v[2]; o[3] = (f16)v[3];
        *(half4*)(d + (size_t)i * 4) = o;
    } else if (bx < WCVT_BLK + ZERO_BLK) {
        int i = (bx - WCVT_BLK) * 256 + tid;
        const f32x4 z4 = {0.f, 0.f, 0.f, 0.f};
        ((f32x4*)dblz)[i] = z4;
    } else {
        const int row = bx - (WCVT_BLK + ZERO_BLK);
        f32x4 u = *(const f32x4*)(X + (size_t)row * DMODEL + tid * 4);
        float ss = u[0]*u[0] + u[1]*u[1] + u[2]*u[2] + u[3]*u[3];
        for (int off = 32; off; off >>= 1) ss += __shfl_down(ss, off, 64);
        __shared__ float red[4];
        if ((tid & 63) == 0) red[tid >> 6] = ss;
        __syncthreads();
        float tot = red[0] + red[1] + red[2] + red[3];
        float scale = rsqrtf(tot * (1.0f / DMODEL) + 1e-5f);
        f32x4 w = *(const f32x4*)(W + tid * 4);
        half4 o;
        o[0] = (f16)(u[0] * scale * w[0]); o[1] = (f16)(u[1] * scale * w[1]);
        o[2] = (f16)(u[2] * scale * w[2]); o[3] = (f16)(u[3] * scale * w[3]);
        *(half4*)(O + (size_t)row * DMODEL + tid * 4) = o;
    }
}

// ---- fp16 GEMM (B^T): C[m,n] = sum_k A[m,k]*Bm[n,k] ------
// tile 128x128, BK=64, 256 thr (4 waves 2x2), mfma_f32_16x16x32_f16.
// AF32: A fp32, fragments converted in-register. EPI 0: split fp16 store.
// EPI 1: fp32 store. EPI 2: atomicAdd fp32. EPI 3: fp16 softplus(acc+fbias).
template <int EPI, int AF32>
__global__ __launch_bounds__(256) void gemm_f16(const void* __restrict__ Ap, int lda,
                                                const f16* __restrict__ Bm, int ldb,
                                                void* __restrict__ C0, void* __restrict__ C1,
                                                int ldc, int N, int klen,
                                                const float* __restrict__ fbias) {
    __shared__ alignas(16) f16 sA[128 * 64];
    __shared__ alignas(16) f16 sB[128 * 64];
    const int tid = threadIdx.x;
    const int wave = tid >> 6, lane = tid & 63;
    const int wm = (wave >> 1) * 64, wn = (wave & 1) * 64;
    const int tm = blockIdx.x, tn = blockIdx.y;
    const int q = lane >> 4, cl = lane & 15;
    const int kbeg = blockIdx.z * klen;

    f32x4 acc[4][4];
    const f32x4 zero4 = {0.f, 0.f, 0.f, 0.f};
#pragma unroll
    for (int t = 0; t < 4; t++)
#pragma unroll
        for (int u = 0; u < 4; u++) acc[t][u] = zero4;

    int rS[4], gkS[4];
#pragma unroll
    for (int j = 0; j < 4; j++) {
        int c = wave * 256 + j * 64 + lane;
        rS[j] = c >> 3;
        gkS[j] = (c & 7) ^ (rS[j] & 7);
    }

    for (int k0 = kbeg; k0 < kbeg + klen; k0 += 64) {
        __syncthreads();
#pragma unroll
        for (int j = 0; j < 4; j++) {
            int ldsoff = (wave * 256 + j * 64) * 8;
            if (!AF32) {
                int ga = tm * 128 + rS[j];
                gload_lds16((const f16*)Ap + (size_t)ga * lda + k0 + gkS[j] * 8, sA + ldsoff);
            }
            int gb = tn * 128 + rS[j];
            if (gb >= N) gb = N - 1;
            gload_lds16(Bm + (size_t)gb * ldb + k0 + gkS[j] * 8, sB + ldsoff);
        }
        __syncthreads();

        half8 af[4][2], bf[4][2];
#pragma unroll
        for (int t = 0; t < 4; t++)
#pragma unroll
            for (int s = 0; s < 2; s++) {
                int m = wm + t * 16 + cl;
                int kc = s * 4 + q;
                if (AF32) {
                    const float* pa = (const float*)Ap + (size_t)(tm * 128 + m) * lda + k0 + kc * 8;
                    f32x4 v0 = *(const f32x4*)pa, v1 = *(const f32x4*)(pa + 4);
                    half8 a;
                    a[0] = (f16)v0[0]; a[1] = (f16)v0[1]; a[2] = (f16)v0[2]; a[3] = (f16)v0[3];
                    a[4] = (f16)v1[0]; a[5] = (f16)v1[1]; a[6] = (f16)v1[2]; a[7] = (f16)v1[3];
                    af[t][s] = a;
                } else {
                    af[t][s] = *(const half8*)(sA + m * 64 + ((kc ^ (m & 7)) << 3));
                }
                int n = wn + t * 16 + cl;
                bf[t][s] = *(const half8*)(sB + n * 64 + ((kc ^ (n & 7)) << 3));
            }
#pragma unroll
        for (int t = 0; t < 4; t++)
#pragma unroll
            for (int u = 0; u < 4; u++) {
                acc[t][u] = __builtin_amdgcn_mfma_f32_16x16x32_f16(af[t][0], bf[u][0], acc[t][u], 0, 0, 0);
                acc[t][u] = __builtin_amdgcn_mfma_f32_16x16x32_f16(af[t][1], bf[u][1], acc[t][u], 0, 0, 0);
            }
    }

    const int rowbase = tm * 128 + wm + q * 4;
    const int colbase = tn * 128 + wn + cl;
#pragma unroll
    for (int t = 0; t < 4; t++)
#pragma unroll
        for (int r = 0; r < 4; r++) {
            size_t rb_ = (size_t)(rowbase + t * 16 + r) * ldc;
            size_t rb1 = (size_t)(rowbase + t * 16 + r) * 1024;
#pragma unroll
            for (int u = 0; u < 4; u++) {
                int gcol = colbase + u * 16;
                float v = acc[t][u][r];
                if (EPI == 0) {
                    if (gcol < 1024) ((f16*)C0)[rb1 + gcol] = (f16)v;
                    else             ((f16*)C1)[rb1 + gcol - 1024] = (f16)v;
                } else if (EPI == 1) {
                    if (gcol < N) ((float*)C0)[rb_ + gcol] = v;
                } else if (EPI == 2) {
                    if (gcol < N) atomicAdd((float*)C0 + rb_ + gcol, v);
                } else {
                    if (gcol < N) {
                        float sv = v + fbias[gcol];
                        sv = (sv > 15.f) ? sv : log1pf(__expf(sv));
                        ((f16*)C0)[rb_ + gcol] = (f16)sv;
                    }
                }
            }
        }
}

// ------- causal depthwise conv (K=4) + bias + silu, 4 rows per thread -------
__global__ __launch_bounds__(256) void conv_silu_kernel(const f16* __restrict__ x,
                                                        const float* __restrict__ cw,
                                                        const float* __restrict__ cb,
                                                        f16* __restrict__ xc) {
    const int rg = blockIdx.x;
    const int d = blockIdx.y * 256 + threadIdx.x;
    const int row0 = rg * 4;
    const int l0 = row0 & (LSEQ - 1);
    float w0 = cw[d * 4], w1 = cw[d * 4 + 1], w2 = cw[d * 4 + 2], w3 = cw[d * 4 + 3];
    float bias = cb[d];
    float v[7];
#pragma unroll
    for (int j = 0; j < 7; j++) {
        int ll = l0 - 3 + j;
        v[j] = (ll >= 0) ? (float)x[(size_t)(row0 - 3 + j) * 1024 + d] : 0.f;
    }
#pragma unroll
    for (int i = 0; i < 4; i++) {
        float acc = bias + w0 * v[i] + w1 * v[i + 1] + w2 * v[i + 2] + w3 * v[i + 3];
        xc[(size_t)(row0 + i) * 1024 + d] = (f16)(acc / (1.f + __expf(-acc)));
    }
}

// ---------------- selective scan: 64 chunks of 32, chunk-major state --------
// state layout: hF/Pb/h0 [c][b][d][n] -> offset ((c*4+b)*1024+d)*8+n
__global__ __launch_bounds__(256) void scan1_kernel(const f16* __restrict__ dt,
                                                    const f16* __restrict__ xc,
                                                    const float* __restrict__ dbl,
                                                    const float* __restrict__ A_log,
                                                    float* __restrict__ hF,
                                                    float* __restrict__ Pb) {
    const int d = blockIdx.x * 256 + threadIdx.x;
    const int c = blockIdx.y;
    const int b = blockIdx.z;
    __shared__ float sB[CHUNKL * NSTATE];   // 256 floats
    sB[threadIdx.x] = dbl[(size_t)(b * LSEQ + c * CHUNKL + (threadIdx.x >> 3)) * 80 + 64 + (threadIdx.x & 7)];
    __syncthreads();
    f32x4 al0 = *(const f32x4*)(A_log + d * 8);
    f32x4 al1 = *(const f32x4*)(A_log + d * 8 + 4);
    float Aa[NSTATE];
#pragma unroll
    for (int n = 0; n < 4; n++) { Aa[n] = -__expf(al0[n]); Aa[n + 4] = -__expf(al1[n]); }
    float h[NSTATE], P[NSTATE];
#pragma unroll
    for (int n = 0; n < NSTATE; n++) { h[n] = 0.f; P[n] = 1.f; }
    const f16* pdt = dt + (size_t)(b * LSEQ + c * CHUNKL) * 1024 + d;
    const f16* pxc = xc + (size_t)(b * LSEQ + c * CHUNKL) * 1024 + d;
    for (int lb = 0; lb < CHUNKL; lb += 8) {
        float vdt[8], vxc[8];
#pragma unroll
        for (int j = 0; j < 8; j++) {       // batch loads: one stall per 8 steps
            vdt[j] = (float)pdt[(size_t)(lb + j) * 1024];
            vxc[j] = (float)pxc[(size_t)(lb + j) * 1024];
        }
#pragma unroll
        for (int j = 0; j < 8; j++) {
            float dtx = vdt[j] * vxc[j];
#pragma unroll
            for (int n = 0; n < NSTATE; n++) {
                float e = __expf(Aa[n] * vdt[j]);
                h[n] = e * h[n] + dtx * sB[(lb + j) * 8 + n];
                P[n] *= e;
            }
        }
    }
    size_t base = ((size_t)(c * 4 + b) * 1024 + d) * 8;
    f32x4 o;
    o[0]=h[0]; o[1]=h[1]; o[2]=h[2]; o[3]=h[3]; *(f32x4*)(hF + base) = o;
    o[0]=h[4]; o[1]=h[5]; o[2]=h[6]; o[3]=h[7]; *(f32x4*)(hF + base + 4) = o;
    o[0]=P[0]; o[1]=P[1]; o[2]=P[2]; o[3]=P[3]; *(f32x4*)(Pb + base) = o;
    o[0]=P[4]; o[1]=P[5]; o[2]=P[6]; o[3]=P[7]; *(f32x4*)(Pb + base + 4) = o;
}

// prefix combine over chunks: thread per (b,d,n), coalesced per c-step
__global__ __launch_bounds__(256) void combine_kernel(const float* __restrict__ hF,
                                                      const float* __restrict__ Pb,
                                                      float* __restrict__ h0) {
    int t = blockIdx.x * 256 + threadIdx.x;   // 32768 = 4b*1024d*8n
    int n = t & 7, dd = (t >> 3) & 1023, b = t >> 13;
    size_t off = (size_t)(b * 1024 + dd) * 8 + n;
    float h = 0.f;
#pragma unroll 8
    for (int c = 0; c < NCHUNK; c++) {
        size_t idx = (size_t)c * 32768 + off;
        h0[idx] = h;
        h = fmaf(Pb[idx], h, hF[idx]);
    }
}

__global__ __launch_bounds__(256) void scan2_kernel(const f16* __restrict__ dt,
                                                    const f16* __restrict__ xc,
                                                    const float* __restrict__ dbl,
                                                    const float* __restrict__ A_log,
                                                    const float* __restrict__ h0,
                                                    const f16* __restrict__ z,
                                                    const float* __restrict__ Dsk,
                                                    f16* __restrict__ yout) {
    const int d = blockIdx.x * 256 + threadIdx.x;
    const int c = blockIdx.y;
    const int b = blockIdx.z;
    __shared__ float sB[CHUNKL * NSTATE];
    __shared__ float sC[CHUNKL * NSTATE];
    {
        size_t rb = (size_t)(b * LSEQ + c * CHUNKL + (threadIdx.x >> 3)) * 80;
        sB[threadIdx.x] = dbl[rb + 64 + (threadIdx.x & 7)];
        sC[threadIdx.x] = dbl[rb + 72 + (threadIdx.x & 7)];
    }
    __syncthreads();
    f32x4 al0 = *(const f32x4*)(A_log + d * 8);
    f32x4 al1 = *(const f32x4*)(A_log + d * 8 + 4);
    float Aa[NSTATE];
#pragma unroll
    for (int n = 0; n < 4; n++) { Aa[n] = -__expf(al0[n]); Aa[n + 4] = -__expf(al1[n]); }
    float h[NSTATE];
    {
        size_t base = ((size_t)(c * 4 + b) * 1024 + d) * 8;
        f32x4 h0a = *(const f32x4*)(h0 + base);
        f32x4 h0b = *(const f32x4*)(h0 + base + 4);
#pragma unroll
        for (int n = 0; n < 4; n++) { h[n] = h0a[n]; h[n + 4] = h0b[n]; }
    }
    const float dval = Dsk[d];
    const size_t rowoff = (size_t)(b * LSEQ + c * CHUNKL) * 1024 + d;
    const f16* pdt = dt + rowoff;
    const f16* pxc = xc + rowoff;
    const f16* pz  = z  + rowoff;
    f16* py = yout + rowoff;
    for (int lb = 0; lb < CHUNKL; lb += 8) {
        float vdt[8], vxc[8], vz[8];
#pragma unroll
        for (int j = 0; j < 8; j++) {
            vdt[j] = (float)pdt[(size_t)(lb + j) * 1024];
            vxc[j] = (float)pxc[(size_t)(lb + j) * 1024];
            vz[j]  = (float)pz[(size_t)(lb + j) * 1024];
        }
#pragma unroll
        for (int j = 0; j < 8; j++) {
            float dtx = vdt[j] * vxc[j];
            float y = 0.f;
#pragma unroll
            for (int n = 0; n < NSTATE; n++) {
                float e = __expf(Aa[n] * vdt[j]);
                h[n] = e * h[n] + dtx * sB[(lb + j) * 8 + n];
                y += h[n] * sC[(lb + j) * 8 + n];
            }
            y += dval * vxc[j];
            y *= vz[j] / (1.f + __expf(-vz[j]));
            py[(size_t)(lb + j) * 1024] = (f16)y;
        }
    }
}

extern "C" void kernel_launch(void* const* d_in, const int* in_sizes, int n_in,
                              void* d_out, int out_size, void* d_ws, size_t ws_size,
                              hipStream_t stream) {
    (void)in_sizes; (void)n_in;
    const float* hidden    = (const float*)d_in[0];
    const float* norm_w    = (const float*)d_in[1];
    const float* in_proj_w = (const float*)d_in[2];
    const float* conv_w    = (const float*)d_in[3];
    const float* conv_b    = (const float*)d_in[4];
    const float* x_proj_w  = (const float*)d_in[5];
    const float* dt_proj_w = (const float*)d_in[6];
    const float* dt_proj_b = (const float*)d_in[7];
    const float* A_log     = (const float*)d_in[8];
    const float* D_skip    = (const float*)d_in[9];
    const float* out_proj_w= (const float*)d_in[10];
    float* out = (float*)d_out;

    if (ws_size < WS_NEED) {
        sentinel_kernel<<<dim3((out_size + 255) / 256), 256, 0, stream>>>(out, out_size);
        return;
    }

    char* ws = (char*)d_ws;
    f16*   xn_h  = (f16*)(ws);                         // [0,16) -> y_h later
    f16*   xbuf_h= (f16*)(ws + (16ull << 20));         // [16,32)
    f16*   zbuf_h= (f16*)(ws + (32ull << 20));         // [32,48)
    f16*   xc_h  = (f16*)(ws + (48ull << 20));         // [48,64)
    f16*   wih   = (f16*)(ws + (64ull << 20));         // [64,68)
    f16*   woh   = (f16*)(ws + (68ull << 20));         // [68,70)
    f16*   wxh   = (f16*)(ws + (70ull << 20));         // 160 KB
    f16*   wdh   = (f16*)(ws + (70ull << 20) + (512ull << 10));  // 128 KB
    float* dbl_f = (float*)(ws + (71ull << 20));       // 2.5 MB
    f16*   dth   = (f16*)(ws + (75ull << 20));         // [75,91)
    float* hF    = (float*)(ws + (91ull << 20));       // 8 MB
    float* Pb    = (float*)(ws + (99ull << 20));       // 8 MB
    float* h0    = (float*)(ws + (107ull << 20));      // 8 MB
    f16*   y_h   = xn_h;

    prep_kernel<<<dim3(WCVT_BLK + ZERO_BLK + NROWS), 256, 0, stream>>>(
        in_proj_w, x_proj_w, dt_proj_w, out_proj_w, wih, wxh, wdh, woh,
        dbl_f, hidden, norm_w, xn_h);
    gemm_f16<0, 0><<<dim3(64, 16), 256, 0, stream>>>(xn_h, 1024, wih, 1024,
                                                     xbuf_h, zbuf_h, 1024, 2048, 1024, nullptr);
    conv_silu_kernel<<<dim3(NROWS / 4, 4), 256, 0, stream>>>(xbuf_h, conv_w, conv_b, xc_h);
    gemm_f16<2, 0><<<dim3(64, 1, 4), 256, 0, stream>>>(xc_h, 1024, wxh, 1024,
                                                       dbl_f, nullptr, 80, 80, 256, nullptr);
    gemm_f16<3, 1><<<dim3(64, 8), 256, 0, stream>>>(dbl_f, 80, wdh, 64,
                                                    dth, nullptr, 1024, 1024, 64, dt_proj_b);
    scan1_kernel<<<dim3(4, NCHUNK, 4), 256, 0, stream>>>(dth, xc_h, dbl_f, A_log, hF, Pb);
    combine_kernel<<<dim3(128), 256, 0, stream>>>(hF, Pb, h0);
    scan2_kernel<<<dim3(4, NCHUNK, 4), 256, 0, stream>>>(dth, xc_h, dbl_f, A_log, h0,
                                                         zbuf_h, D_skip, y_h);
    gemm_f16<1, 0><<<dim3(64, 8), 256, 0, stream>>>(y_h, 1024, woh, 1024,
                                                    out, nullptr, 1024, 1024, 1024, nullptr);
}